// Round 5
// baseline (537.717 us; speedup 1.0000x reference)
//
#include <hip/hip_runtime.h>
#include <stdint.h>

#define NROW 8192
#define DIM  512
#define NOUT 16
#define GAMMA 0.001f
// exp(2*gamma*c) = exp2(c * 2*gamma*log2(e))
#define EXP2S (2.0f * GAMMA * 1.44269504088896340736f)

typedef __bf16 bf16_t;
typedef bf16_t bf16x4_t __attribute__((ext_vector_type(4)));
typedef bf16_t bf16x8_t __attribute__((ext_vector_type(8)));
typedef float  floatx4_t __attribute__((ext_vector_type(4)));

// ---------- prep: fp32 -> bf16 rows, exp(-g*||row||^2), fused alpha' ----------
__global__ __launch_bounds__(256) void prep_convert(
    const float* __restrict__ X, const float* __restrict__ T,
    const float* __restrict__ alpha,
    bf16_t* __restrict__ Xb, bf16_t* __restrict__ Tb,
    float* __restrict__ xfac, bf16_t* __restrict__ alphaTp)
{
    const int w = threadIdx.x >> 6, lane = threadIdx.x & 63;
    const int row = blockIdx.x * 4 + w;              // 0..16383
    const bool is_test = row < NROW;
    const float* src = is_test ? X : T;
    bf16_t* dst = is_test ? Xb : Tb;
    const int r = is_test ? row : row - NROW;
    const float4* s4 = (const float4*)(src + (size_t)r * DIM);
    const float4 v0 = s4[lane];
    const float4 v1 = s4[lane + 64];
    float ss = v0.x*v0.x + v0.y*v0.y + v0.z*v0.z + v0.w*v0.w
             + v1.x*v1.x + v1.y*v1.y + v1.z*v1.z + v1.w*v1.w;
    bf16x4_t o0 = { (bf16_t)v0.x, (bf16_t)v0.y, (bf16_t)v0.z, (bf16_t)v0.w };
    bf16x4_t o1 = { (bf16_t)v1.x, (bf16_t)v1.y, (bf16_t)v1.z, (bf16_t)v1.w };
    bf16x4_t* d4 = (bf16x4_t*)(dst + (size_t)r * DIM);
    d4[lane] = o0;
    d4[lane + 64] = o1;
#pragma unroll
    for (int m = 32; m > 0; m >>= 1) ss += __shfl_xor(ss, m, 64);
    const float f = __expf(-GAMMA * ss);             // all lanes hold the sum
    if (is_test) {
        if (lane == 0) xfac[r] = f;
    } else if (lane < 16) {
        // alphaT'[o][j] = exp(-g*||y_j||^2) * alpha[j][o]
        alphaTp[(size_t)lane * NROW + r] = (bf16_t)(alpha[r * 16 + lane] * f);
    }
}

// ---------- main: barrier-free K-loop, frags loaded straight from L2 ----------
// mfma_16x16x32 A/B frag = 16 contiguous bytes at [row][k0+quad*8] -> direct
// global loads of row-major bf16, no LDS staging, ZERO __syncthreads in the
// K-loop. X slice is L2-resident per XCD (grid.x = rb); T streams, in-block
// 2x duplication absorbed by L1. 2-deep register double-buffer hides L2 lat.
#define TPT 2        // train tiles per block (32 chunks x 2 tiles = 8192)
#define KLD2 72      // padded row stride (bf16) of per-wave K'' tile

__global__ __launch_bounds__(256, 3) void rbf_main(
    const bf16_t* __restrict__ Xb, const bf16_t* __restrict__ Tb,
    const bf16_t* __restrict__ alphaTp, const float* __restrict__ xfac,
    float* __restrict__ out)
{
    // kw: 4 waves x K''[64 test][72 train-padded] bf16 = 36 KB (stash unions)
    __shared__ __align__(16) unsigned char smem[4 * 64 * KLD2 * 2];

    const int tid = threadIdx.x;
    const int w = tid >> 6, lane = tid & 63;
    const int wm = w >> 1, wn = w & 1;               // train half / test half
    const int quad = lane >> 4, l15 = lane & 15;

    const int rb = blockIdx.x;                       // 0..63  test block (XCD = rb%8)
    const int chunk = blockIdx.y;                    // 0..31  train chunk
    const int row0 = rb * 128;
    const int cb0 = chunk * (TPT * 128);

    // per-lane frag row pointers (quad k-offset folded in); k0 goes in the imm
    const bf16_t* tp[4];
    const bf16_t* xp[4];
#pragma unroll
    for (int i = 0; i < 4; ++i) {
        tp[i] = Tb + (size_t)(cb0 + wm * 64 + i * 16 + l15) * DIM + quad * 8;
        xp[i] = Xb + (size_t)(row0 + wn * 64 + i * 16 + l15) * DIM + quad * 8;
    }

    const floatx4_t vzero = {0.f, 0.f, 0.f, 0.f};
    floatx4_t oacc[4];
#pragma unroll
    for (int i = 0; i < 4; ++i) oacc[i] = vzero;

    bf16_t* kw = (bf16_t*)smem + w * (64 * KLD2);    // wave-private K'' region

    for (int t = 0; t < TPT; ++t) {
        const int cb = cb0 + t * 128;

        floatx4_t acc[4][4];
#pragma unroll
        for (int i = 0; i < 4; ++i)
#pragma unroll
            for (int j = 0; j < 4; ++j) acc[i][j] = vzero;

        // epilogue B-frags for this tile (L2-resident, 256 KB table)
        const bf16_t* ap = alphaTp + (size_t)l15 * NROW + cb + wm * 64 + quad * 8;
        const bf16x8_t bv0 = *(const bf16x8_t*)(ap);
        const bf16x8_t bv1 = *(const bf16x8_t*)(ap + 32);

        bf16x8_t a0[4], b0[4], a1[4], b1[4];
#pragma unroll
        for (int i = 0; i < 4; ++i) {
            a0[i] = *(const bf16x8_t*)(tp[i]);
            b0[i] = *(const bf16x8_t*)(xp[i]);
        }

#pragma unroll
        for (int kk = 0; kk < 8; ++kk) {             // two 32-k steps per kk
            const int kA = kk * 64 + 32;             // byte imm = 2*kA <= 960
#pragma unroll
            for (int i = 0; i < 4; ++i) {
                a1[i] = *(const bf16x8_t*)(tp[i] + kA);
                b1[i] = *(const bf16x8_t*)(xp[i] + kA);
            }
#pragma unroll
            for (int mi = 0; mi < 4; ++mi)
#pragma unroll
                for (int ni = 0; ni < 4; ++ni)
                    acc[mi][ni] = __builtin_amdgcn_mfma_f32_16x16x32_bf16(
                        a0[mi], b0[ni], acc[mi][ni], 0, 0, 0);
            if (kk < 7) {
                const int kB = kk * 64 + 64;
#pragma unroll
                for (int i = 0; i < 4; ++i) {
                    a0[i] = *(const bf16x8_t*)(tp[i] + kB);
                    b0[i] = *(const bf16x8_t*)(xp[i] + kB);
                }
            }
#pragma unroll
            for (int mi = 0; mi < 4; ++mi)
#pragma unroll
                for (int ni = 0; ni < 4; ++ni)
                    acc[mi][ni] = __builtin_amdgcn_mfma_f32_16x16x32_bf16(
                        a1[mi], b1[ni], acc[mi][ni], 0, 0, 0);
        }
#pragma unroll
        for (int i = 0; i < 4; ++i) tp[i] += 128 * DIM;   // next train tile

        // K'' = exp(2*gamma*cross) -> bf16, wave-private LDS (no barrier needed:
        // in-wave lgkmcnt orders prior epilogue reads before these writes)
        // acc[mi][ni][r] = cross[train = mi*16+quad*4+r][test = ni*16+l15]
#pragma unroll
        for (int ni = 0; ni < 4; ++ni)
#pragma unroll
            for (int mi = 0; mi < 4; ++mi) {
                bf16x4_t pk;
#pragma unroll
                for (int r = 0; r < 4; ++r)
                    pk[r] = (bf16_t)__builtin_amdgcn_exp2f(acc[mi][ni][r] * EXP2S);
                *(bf16x4_t*)(kw + (ni * 16 + l15) * KLD2 + mi * 16 + quad * 4) = pk;
            }

        // epilogue: oacc[ni] += K''[test 16(ni) x train 64] @ alpha'[64 x 16]
#pragma unroll
        for (int ni = 0; ni < 4; ++ni) {
            const bf16x8_t av0 = *(const bf16x8_t*)(kw + (ni * 16 + l15) * KLD2 + quad * 8);
            oacc[ni] = __builtin_amdgcn_mfma_f32_16x16x32_bf16(av0, bv0, oacc[ni], 0, 0, 0);
        }
#pragma unroll
        for (int ni = 0; ni < 4; ++ni) {
            const bf16x8_t av1 = *(const bf16x8_t*)(kw + (ni * 16 + l15) * KLD2 + 32 + quad * 8);
            oacc[ni] = __builtin_amdgcn_mfma_f32_16x16x32_bf16(av1, bv1, oacc[ni], 0, 0, 0);
        }
    }

    // reduce the two train halves (wm=0,1) through LDS, then atomicAdd to out
    __syncthreads();
    float* stash = (float*)smem;
    if (wm == 1) {
#pragma unroll
        for (int ni = 0; ni < 4; ++ni)
            *(floatx4_t*)(stash + wn * 1024 + ni * 256 + lane * 4) = oacc[ni];
    }
    __syncthreads();
    if (wm == 0) {
#pragma unroll
        for (int ni = 0; ni < 4; ++ni) {
            const floatx4_t o2 = *(const floatx4_t*)(stash + wn * 1024 + ni * 256 + lane * 4);
            const int trow = row0 + wn * 64 + ni * 16 + quad * 4;
            const float4 xf = *(const float4*)(xfac + trow);
            atomicAdd(out + (size_t)(trow + 0) * NOUT + l15, (oacc[ni][0] + o2[0]) * xf.x);
            atomicAdd(out + (size_t)(trow + 1) * NOUT + l15, (oacc[ni][1] + o2[1]) * xf.y);
            atomicAdd(out + (size_t)(trow + 2) * NOUT + l15, (oacc[ni][2] + o2[2]) * xf.z);
            atomicAdd(out + (size_t)(trow + 3) * NOUT + l15, (oacc[ni][3] + o2[3]) * xf.w);
        }
    }
}

extern "C" void kernel_launch(void* const* d_in, const int* in_sizes, int n_in,
                              void* d_out, int out_size, void* d_ws, size_t ws_size,
                              hipStream_t stream) {
    (void)in_sizes; (void)n_in; (void)out_size; (void)ws_size;
    const float* X     = (const float*)d_in[0];
    const float* T     = (const float*)d_in[1];
    const float* alpha = (const float*)d_in[2];

    char* ws = (char*)d_ws;
    bf16_t* Xb      = (bf16_t*)ws;                                   // 8 MB
    bf16_t* Tb      = (bf16_t*)(ws + (8u << 20));                    // 8 MB
    float*  xfac    = (float*)(ws + (16u << 20));                    // 32 KB
    bf16_t* alphaTp = (bf16_t*)(ws + (16u << 20) + (64u << 10));     // 256 KB
    float*  out     = (float*)d_out;

    hipMemsetAsync(out, 0, (size_t)NROW * NOUT * sizeof(float), stream);
    prep_convert<<<4096, 256, 0, stream>>>(X, T, alpha, Xb, Tb, xfac, alphaTp);
    dim3 grid(64, 32);   // x = rb (XCD affinity for X), y = chunk
    rbf_main<<<grid, 256, 0, stream>>>(Xb, Tb, alphaTp, xfac, out);
}

// Round 6
// 184.480 us; speedup vs baseline: 2.9148x; 2.9148x over previous
//
#include <hip/hip_runtime.h>
#include <stdint.h>

#define NROW 8192
#define DIM  512
#define NOUT 16
#define GAMMA 0.001f
// exp(2*gamma*c) = exp2(c * 2*gamma*log2(e))
#define EXP2S (2.0f * GAMMA * 1.44269504088896340736f)

typedef __bf16 bf16_t;
typedef bf16_t bf16x4_t __attribute__((ext_vector_type(4)));
typedef bf16_t bf16x8_t __attribute__((ext_vector_type(8)));
typedef float  floatx4_t __attribute__((ext_vector_type(4)));

// async global->LDS, 16 B/lane. LDS dest is wave-uniform base + lane*16.
__device__ __forceinline__ void async_copy16(const void* g, const void* l) {
    __builtin_amdgcn_global_load_lds(
        (__attribute__((address_space(1))) void*)(uintptr_t)g,
        (__attribute__((address_space(3))) void*)(uint32_t)(uintptr_t)l,
        16, 0, 0);
}

// ---------- prep: fp32 -> bf16 rows, exp(-g*||row||^2), fused alpha' ----------
__global__ __launch_bounds__(256) void prep_convert(
    const float* __restrict__ X, const float* __restrict__ T,
    const float* __restrict__ alpha,
    bf16_t* __restrict__ Xb, bf16_t* __restrict__ Tb,
    float* __restrict__ xfac, bf16_t* __restrict__ alphaTp)
{
    const int w = threadIdx.x >> 6, lane = threadIdx.x & 63;
    const int row = blockIdx.x * 4 + w;              // 0..16383
    const bool is_test = row < NROW;
    const float* src = is_test ? X : T;
    bf16_t* dst = is_test ? Xb : Tb;
    const int r = is_test ? row : row - NROW;
    const float4* s4 = (const float4*)(src + (size_t)r * DIM);
    const float4 v0 = s4[lane];
    const float4 v1 = s4[lane + 64];
    float ss = v0.x*v0.x + v0.y*v0.y + v0.z*v0.z + v0.w*v0.w
             + v1.x*v1.x + v1.y*v1.y + v1.z*v1.z + v1.w*v1.w;
    bf16x4_t o0 = { (bf16_t)v0.x, (bf16_t)v0.y, (bf16_t)v0.z, (bf16_t)v0.w };
    bf16x4_t o1 = { (bf16_t)v1.x, (bf16_t)v1.y, (bf16_t)v1.z, (bf16_t)v1.w };
    bf16x4_t* d4 = (bf16x4_t*)(dst + (size_t)r * DIM);
    d4[lane] = o0;
    d4[lane + 64] = o1;
#pragma unroll
    for (int m = 32; m > 0; m >>= 1) ss += __shfl_xor(ss, m, 64);
    const float f = __expf(-GAMMA * ss);             // all lanes hold the sum
    if (is_test) {
        if (lane == 0) xfac[r] = f;
    } else if (lane < 16) {
        // alphaT'[o][j] = exp(-g*||y_j||^2) * alpha[j][o]
        alphaTp[(size_t)lane * NROW + r] = (bf16_t)(alpha[r * 16 + lane] * f);
    }
}

// ---------- main: 128x128 bf16 MFMA GEMM + fused exp + @alpha' epilogue ----------
// r3 structure (best measured: 127 us) with ONE change: __launch_bounds__(256,3).
// r3 at (256,4) had 128-reg budget < ~134 live regs -> ~112 MB of scratch spill
// traffic (WRITE_SIZE evidence), while only achieving ~3.1 blocks/CU anyway.
// (256,3) gives ~168 regs -> no spills at the same effective occupancy.
#define BK 64
#define TPT 4        // train tiles per block (16 chunks x 4 tiles = 8192)
#define KLD2 72      // padded row stride (bf16) of per-wave K'' tile [test 64][train 64]

__global__ __launch_bounds__(256, 3) void rbf_main(
    const bf16_t* __restrict__ Xb, const bf16_t* __restrict__ Tb,
    const bf16_t* __restrict__ alphaTp, const float* __restrict__ xfac,
    float* __restrict__ out)
{
    // union: staging Ts[128][64](16KB)+Xs[128][64](16KB)  vs  4 waves x K''[64][72]
    __shared__ __align__(16) unsigned char smem[4 * 64 * KLD2 * 2];   // 36864 B

    const int tid = threadIdx.x;
    const int w = tid >> 6, lane = tid & 63;
    const int wm = w >> 1, wn = w & 1;               // train half / test half
    const int quad = lane >> 4, l15 = lane & 15;

    const int rb = blockIdx.x;                       // 0..63   test block (XCD = rb%8)
    const int chunk = blockIdx.y;                    // 0..15   train chunk
    const int row0 = rb * 128;                       // test base row

    // staging slot s = tid + i*256: row = i*32 + (tid>>3), LDS col16 = tid&7,
    // global col16 = (tid&7) ^ (row&7)   (XOR swizzle)
    const int s_row = tid >> 3;                      // 0..31
    const int g_colb = (((tid & 7) ^ (s_row & 7)) * 16);
    const char* gX = (const char*)(Xb + (size_t)(row0 + s_row) * DIM) + g_colb;
    const unsigned ldsW = (unsigned)(w << 10);       // wave base within each 4KB issue-slab

    const floatx4_t vzero = {0.f, 0.f, 0.f, 0.f};
    floatx4_t oacc[4];
#pragma unroll
    for (int i = 0; i < 4; ++i) oacc[i] = vzero;

    bf16_t* kw = (bf16_t*)smem + w * (64 * KLD2);    // this wave's K'' region

    for (int t = 0; t < TPT; ++t) {
        const int cb = chunk * (TPT * 128) + t * 128;    // train base row
        const char* gT = (const char*)(Tb + (size_t)(cb + s_row) * DIM) + g_colb;

        floatx4_t acc[4][4];
#pragma unroll
        for (int i = 0; i < 4; ++i)
#pragma unroll
            for (int j = 0; j < 4; ++j) acc[i][j] = vzero;

        for (int kb = 0; kb < DIM * 2; kb += BK * 2) {   // byte offset along K: 8 iters
            __syncthreads();                             // prev LDS reads done
#pragma unroll
            for (int i = 0; i < 4; ++i) {
                async_copy16(gT + (size_t)i * 32768 + kb, smem + i * 4096 + ldsW);
                async_copy16(gX + (size_t)i * 32768 + kb, smem + 16384 + i * 4096 + ldsW);
            }
            __syncthreads();                             // drains vmcnt: loads landed

            // two k-halves of 32; frag for k-half h at global col16 g = h*4+quad,
            // physical col16 p = g ^ (row&7), row&7 == l15&7 here
#pragma unroll
            for (int h = 0; h < 2; ++h) {
                const int xs = (((h * 4 + quad) ^ (l15 & 7)) * 16);
                bf16x8_t af[4], bfv[4];
#pragma unroll
                for (int i = 0; i < 4; ++i) {
                    af[i]  = *(const bf16x8_t*)(smem + (wm * 64 + i * 16 + l15) * 128 + xs);
                    bfv[i] = *(const bf16x8_t*)(smem + 16384 + (wn * 64 + i * 16 + l15) * 128 + xs);
                }
#pragma unroll
                for (int mi = 0; mi < 4; ++mi)
#pragma unroll
                    for (int ni = 0; ni < 4; ++ni)
                        acc[mi][ni] = __builtin_amdgcn_mfma_f32_16x16x32_bf16(
                            af[mi], bfv[ni], acc[mi][ni], 0, 0, 0);
            }
        }

        __syncthreads();   // all frag reads of Ts/Xs done before overwrite with K''
        // K'' = exp(2*gamma*cross), bf16, test-major: kw[test][train], 8B packed stores
        // acc[mi][ni][r] = cross[train = mi*16+quad*4+r][test = ni*16+l15]
#pragma unroll
        for (int ni = 0; ni < 4; ++ni)
#pragma unroll
            for (int mi = 0; mi < 4; ++mi) {
                bf16x4_t pk;
#pragma unroll
                for (int r = 0; r < 4; ++r)
                    pk[r] = (bf16_t)__builtin_amdgcn_exp2f(acc[mi][ni][r] * EXP2S);
                *(bf16x4_t*)(kw + (ni * 16 + l15) * KLD2 + mi * 16 + quad * 4) = pk;
            }
        // no barrier: each wave reads only its own kw region (in-wave lgkmcnt orders)

        // epilogue: oacc[ni] += K''[test 16(ni) x train 64] @ alpha'[train 64 x o 16]
#pragma unroll
        for (int ks = 0; ks < 2; ++ks) {
            const bf16x8_t bv = *(const bf16x8_t*)(alphaTp + (size_t)l15 * NROW
                                                   + cb + wm * 64 + ks * 32 + quad * 8);
#pragma unroll
            for (int ni = 0; ni < 4; ++ni) {
                const bf16x8_t av = *(const bf16x8_t*)(kw + (ni * 16 + l15) * KLD2
                                                       + ks * 32 + quad * 8);
                oacc[ni] = __builtin_amdgcn_mfma_f32_16x16x32_bf16(av, bv, oacc[ni], 0, 0, 0);
            }
        }
        // next t: leading __syncthreads() protects kw reads vs restaging
    }

    // reduce the two train halves (wm=0,1) through LDS, then atomicAdd to out
    __syncthreads();
    float* stash = (float*)smem;
    if (wm == 1) {
#pragma unroll
        for (int ni = 0; ni < 4; ++ni)
            *(floatx4_t*)(stash + wn * 1024 + ni * 256 + lane * 4) = oacc[ni];
    }
    __syncthreads();
    if (wm == 0) {
#pragma unroll
        for (int ni = 0; ni < 4; ++ni) {
            const floatx4_t o2 = *(const floatx4_t*)(stash + wn * 1024 + ni * 256 + lane * 4);
            const int trow = row0 + wn * 64 + ni * 16 + quad * 4;
            const float4 xf = *(const float4*)(xfac + trow);
            atomicAdd(out + (size_t)(trow + 0) * NOUT + l15, (oacc[ni][0] + o2[0]) * xf.x);
            atomicAdd(out + (size_t)(trow + 1) * NOUT + l15, (oacc[ni][1] + o2[1]) * xf.y);
            atomicAdd(out + (size_t)(trow + 2) * NOUT + l15, (oacc[ni][2] + o2[2]) * xf.z);
            atomicAdd(out + (size_t)(trow + 3) * NOUT + l15, (oacc[ni][3] + o2[3]) * xf.w);
        }
    }
}

extern "C" void kernel_launch(void* const* d_in, const int* in_sizes, int n_in,
                              void* d_out, int out_size, void* d_ws, size_t ws_size,
                              hipStream_t stream) {
    (void)in_sizes; (void)n_in; (void)out_size; (void)ws_size;
    const float* X     = (const float*)d_in[0];
    const float* T     = (const float*)d_in[1];
    const float* alpha = (const float*)d_in[2];

    char* ws = (char*)d_ws;
    bf16_t* Xb      = (bf16_t*)ws;                                   // 8 MB
    bf16_t* Tb      = (bf16_t*)(ws + (8u << 20));                    // 8 MB
    float*  xfac    = (float*)(ws + (16u << 20));                    // 32 KB
    bf16_t* alphaTp = (bf16_t*)(ws + (16u << 20) + (64u << 10));     // 256 KB
    float*  out     = (float*)d_out;

    hipMemsetAsync(out, 0, (size_t)NROW * NOUT * sizeof(float), stream);
    prep_convert<<<4096, 256, 0, stream>>>(X, T, alpha, Xb, Tb, xfac, alphaTp);
    dim3 grid(64, 16);   // x = rb (XCD affinity for X), y = chunk
    rbf_main<<<grid, 256, 0, stream>>>(Xb, Tb, alphaTp, xfac, out);
}

// Round 7
// 129.254 us; speedup vs baseline: 4.1602x; 1.4273x over previous
//
#include <hip/hip_runtime.h>
#include <stdint.h>

#define NROW 8192
#define DIM  512
#define NOUT 16
#define GAMMA 0.001f
// exp(2*gamma*c) = exp2(c * 2*gamma*log2(e))
#define EXP2S (2.0f * GAMMA * 1.44269504088896340736f)

typedef __bf16 bf16_t;
typedef bf16_t bf16x4_t __attribute__((ext_vector_type(4)));
typedef bf16_t bf16x8_t __attribute__((ext_vector_type(8)));
typedef float  floatx4_t __attribute__((ext_vector_type(4)));
typedef long   longx2_t __attribute__((ext_vector_type(2)));

// async global->LDS, 16 B/lane. LDS dest is wave-uniform base + lane*16.
__device__ __forceinline__ void async_copy16(const void* g, const void* l) {
    __builtin_amdgcn_global_load_lds(
        (__attribute__((address_space(1))) void*)(uintptr_t)g,
        (__attribute__((address_space(3))) void*)(uint32_t)(uintptr_t)l,
        16, 0, 0);
}

// ---------- prep: fp32 -> fp8 e4m3 rows (K-permuted), norms, alpha' ----------
// Per 64-k group, byte layout: unit u(0..3) of 16B = [kstep0 chunk u (8B) |
// kstep1 chunk u (8B)] so one ds_read_b128 yields both 16x16x32 fp8 operands.
__global__ __launch_bounds__(256) void prep_convert(
    const float* __restrict__ X, const float* __restrict__ T,
    const float* __restrict__ alpha,
    uint8_t* __restrict__ Xf, uint8_t* __restrict__ Tf,
    float* __restrict__ xfac, bf16_t* __restrict__ alphaTp)
{
    const int w = threadIdx.x >> 6, lane = threadIdx.x & 63;
    const int row = blockIdx.x * 4 + w;              // 0..16383
    const bool is_test = row < NROW;
    const float* src = is_test ? X : T;
    uint8_t* dst = is_test ? Xf : Tf;
    const int r = is_test ? row : row - NROW;
    // lane owns floats [lane*8, lane*8+8) = one 8-byte fp8 chunk
    const float4* s4 = (const float4*)(src + (size_t)r * DIM);
    const float4 v0 = s4[lane * 2];
    const float4 v1 = s4[lane * 2 + 1];
    float ss = v0.x*v0.x + v0.y*v0.y + v0.z*v0.z + v0.w*v0.w
             + v1.x*v1.x + v1.y*v1.y + v1.z*v1.z + v1.w*v1.w;
    int lo = __builtin_amdgcn_cvt_pk_fp8_f32(v0.x, v0.y, 0, false);
    lo     = __builtin_amdgcn_cvt_pk_fp8_f32(v0.z, v0.w, lo, true);
    int hi = __builtin_amdgcn_cvt_pk_fp8_f32(v1.x, v1.y, 0, false);
    hi     = __builtin_amdgcn_cvt_pk_fp8_f32(v1.z, v1.w, hi, true);
    // chunk m = lane: group g = m>>3, half h = (m>>2)&1, unit u = m&3
    const int off = (lane >> 3) * 64 + (lane & 3) * 16 + ((lane >> 2) & 1) * 8;
    *(int2*)(dst + (size_t)r * DIM + off) = make_int2(lo, hi);
#pragma unroll
    for (int m = 32; m > 0; m >>= 1) ss += __shfl_xor(ss, m, 64);
    const float f = __expf(-GAMMA * ss);             // all lanes hold the sum
    if (is_test) {
        if (lane == 0) xfac[r] = f;
    } else if (lane < 16) {
        // alphaT'[o][j] = exp(-g*||y_j||^2) * alpha[j][o]
        alphaTp[(size_t)lane * NROW + r] = (bf16_t)(alpha[r * 16 + lane] * f);
    }
}

// ---------- main: fp8 128x128 MFMA GEMM, double-buffered pipelined staging ----
// Per k-iter: sync; issue async loads into buf[g+1]; compute buf[g]. The
// vmcnt(0)-at-barrier then drains loads that had a full compute phase of
// cover -> near-zero stall (vs r6's stage->sync->compute convoy). fp8 halves
// both staging bytes and frag ds_read traffic. Epilogue stays bf16.
#define TPT 4        // train tiles per block (16 chunks x 4 tiles = 8192)
#define KLD2 72      // padded row stride (bf16) of per-wave K'' tile

__global__ __launch_bounds__(256, 3) void rbf_main(
    const uint8_t* __restrict__ Xf, const uint8_t* __restrict__ Tf,
    const bf16_t* __restrict__ alphaTp, const float* __restrict__ xfac,
    float* __restrict__ out)
{
    // layout: buf0 [0,16K) = T 8K | X 8K ; buf1 [16K,32K) ; kw 4x9216 B unions
    __shared__ __align__(16) unsigned char smem[4 * 64 * KLD2 * 2];   // 36864 B

    const int tid = threadIdx.x;
    const int w = tid >> 6, lane = tid & 63;
    const int wm = w >> 1, wn = w & 1;               // train half / test half
    const int quad = lane >> 4, l15 = lane & 15;

    const int rb = blockIdx.x;                       // 0..63  test block (XCD = rb%8)
    const int chunk = blockIdx.y;                    // 0..15  train chunk
    const int row0 = rb * 128;
    const int cb0 = chunk * (TPT * 128);

    // staging slot: s_row = tid>>2 (0..63, +64 for 2nd issue), unit = tid&3,
    // global unit = (tid&3) ^ ((row>>1)&3)  (XOR swizzle; invariant under +64)
    const int s_row = tid >> 2;
    const int g_off = (((tid & 3) ^ ((s_row >> 1) & 3)) * 16);
    const uint8_t* gX = Xf + (size_t)(row0 + s_row) * DIM + g_off;
    const uint8_t* gT = Tf + (size_t)(cb0 + s_row) * DIM + g_off;
    const unsigned ldsW = (unsigned)(w << 10);       // wave base in each 4KB slab

    // frag-read swizzle: phys unit16 = quad ^ ((l15>>1)&3)  -> 2-way (free)
    const int xs = ((quad ^ ((l15 >> 1) & 3)) * 16);

    const floatx4_t vzero = {0.f, 0.f, 0.f, 0.f};
    floatx4_t oacc[4];
#pragma unroll
    for (int i = 0; i < 4; ++i) oacc[i] = vzero;

    bf16_t* kw = (bf16_t*)smem + w * (64 * KLD2);    // wave-private K'' region

    for (int t = 0; t < TPT; ++t) {
        const int cb = cb0 + t * 128;
        const uint8_t* gTt = gT + (size_t)t * 128 * DIM;

        floatx4_t acc[4][4];
#pragma unroll
        for (int i = 0; i < 4; ++i)
#pragma unroll
            for (int j = 0; j < 4; ++j) acc[i][j] = vzero;

        __syncthreads();             // all waves done with kw/stash before restage
        // prime: k-group 0 -> buf0
#pragma unroll
        for (int i = 0; i < 2; ++i) {
            async_copy16(gTt + (size_t)i * 64 * DIM, smem + i * 4096 + ldsW);
            async_copy16(gX  + (size_t)i * 64 * DIM, smem + 8192 + i * 4096 + ldsW);
        }

#pragma unroll
        for (int g = 0; g < 8; ++g) {
            __syncthreads();         // drains vmcnt: buf[g&1] landed (covered issue)
            if (g < 7) {             // issue g+1 into the other buffer
                unsigned bn = ((g + 1) & 1) * 16384u;
                const int kb = (g + 1) * 64;
#pragma unroll
                for (int i = 0; i < 2; ++i) {
                    async_copy16(gTt + (size_t)i * 64 * DIM + kb, smem + bn + i * 4096 + ldsW);
                    async_copy16(gX  + (size_t)i * 64 * DIM + kb, smem + bn + 8192 + i * 4096 + ldsW);
                }
            }
            const unsigned char* bufc = smem + (g & 1) * 16384;
            longx2_t ta[4], xb[4];
#pragma unroll
            for (int i = 0; i < 4; ++i) {
                ta[i] = *(const longx2_t*)(bufc + (wm * 64 + i * 16 + l15) * 64 + xs);
                xb[i] = *(const longx2_t*)(bufc + 8192 + (wn * 64 + i * 16 + l15) * 64 + xs);
            }
#pragma unroll
            for (int mi = 0; mi < 4; ++mi)
#pragma unroll
                for (int ni = 0; ni < 4; ++ni)
                    acc[mi][ni] = __builtin_amdgcn_mfma_f32_16x16x32_fp8_fp8(
                        ta[mi].x, xb[ni].x, acc[mi][ni], 0, 0, 0);
#pragma unroll
            for (int mi = 0; mi < 4; ++mi)
#pragma unroll
                for (int ni = 0; ni < 4; ++ni)
                    acc[mi][ni] = __builtin_amdgcn_mfma_f32_16x16x32_fp8_fp8(
                        ta[mi].y, xb[ni].y, acc[mi][ni], 0, 0, 0);
        }

        __syncthreads();   // all frag reads done before kw overwrites bufs
        // K'' = exp(2*gamma*cross), bf16, test-major kw[test][train], 8B stores
        // acc[mi][ni][r] = cross[train = mi*16+quad*4+r][test = ni*16+l15]
#pragma unroll
        for (int ni = 0; ni < 4; ++ni)
#pragma unroll
            for (int mi = 0; mi < 4; ++mi) {
                bf16x4_t pk;
#pragma unroll
                for (int r = 0; r < 4; ++r)
                    pk[r] = (bf16_t)__builtin_amdgcn_exp2f(acc[mi][ni][r] * EXP2S);
                *(bf16x4_t*)(kw + (ni * 16 + l15) * KLD2 + mi * 16 + quad * 4) = pk;
            }
        // no barrier: each wave reads only its own kw region (in-wave lgkmcnt)

        // epilogue: oacc[ni] += K''[test 16(ni) x train 64] @ alpha'[64 x 16]
#pragma unroll
        for (int ks = 0; ks < 2; ++ks) {
            const bf16x8_t bv = *(const bf16x8_t*)(alphaTp + (size_t)l15 * NROW
                                                   + cb + wm * 64 + ks * 32 + quad * 8);
#pragma unroll
            for (int ni = 0; ni < 4; ++ni) {
                const bf16x8_t av = *(const bf16x8_t*)(kw + (ni * 16 + l15) * KLD2
                                                       + ks * 32 + quad * 8);
                oacc[ni] = __builtin_amdgcn_mfma_f32_16x16x32_bf16(av, bv, oacc[ni], 0, 0, 0);
            }
        }
        // next t: leading __syncthreads() protects kw reads vs restaging
    }

    // reduce the two train halves (wm=0,1) through LDS, then atomicAdd to out
    __syncthreads();
    float* stash = (float*)smem;
    if (wm == 1) {
#pragma unroll
        for (int ni = 0; ni < 4; ++ni)
            *(floatx4_t*)(stash + wn * 1024 + ni * 256 + lane * 4) = oacc[ni];
    }
    __syncthreads();
    if (wm == 0) {
#pragma unroll
        for (int ni = 0; ni < 4; ++ni) {
            const floatx4_t o2 = *(const floatx4_t*)(stash + wn * 1024 + ni * 256 + lane * 4);
            const int trow = row0 + wn * 64 + ni * 16 + quad * 4;
            const float4 xf = *(const float4*)(xfac + trow);
            atomicAdd(out + (size_t)(trow + 0) * NOUT + l15, (oacc[ni][0] + o2[0]) * xf.x);
            atomicAdd(out + (size_t)(trow + 1) * NOUT + l15, (oacc[ni][1] + o2[1]) * xf.y);
            atomicAdd(out + (size_t)(trow + 2) * NOUT + l15, (oacc[ni][2] + o2[2]) * xf.z);
            atomicAdd(out + (size_t)(trow + 3) * NOUT + l15, (oacc[ni][3] + o2[3]) * xf.w);
        }
    }
}

extern "C" void kernel_launch(void* const* d_in, const int* in_sizes, int n_in,
                              void* d_out, int out_size, void* d_ws, size_t ws_size,
                              hipStream_t stream) {
    (void)in_sizes; (void)n_in; (void)out_size; (void)ws_size;
    const float* X     = (const float*)d_in[0];
    const float* T     = (const float*)d_in[1];
    const float* alpha = (const float*)d_in[2];

    char* ws = (char*)d_ws;
    uint8_t* Xf     = (uint8_t*)ws;                                  // 4 MB
    uint8_t* Tf     = (uint8_t*)(ws + (8u << 20));                   // 4 MB
    float*   xfac   = (float*)(ws + (16u << 20));                    // 32 KB
    bf16_t*  alphaTp= (bf16_t*)(ws + (16u << 20) + (64u << 10));     // 256 KB
    float*   out    = (float*)d_out;

    hipMemsetAsync(out, 0, (size_t)NROW * NOUT * sizeof(float), stream);
    prep_convert<<<4096, 256, 0, stream>>>(X, T, alpha, Xf, Tf, xfac, alphaTp);
    dim3 grid(64, 16);   // x = rb (XCD affinity for X), y = chunk
    rbf_main<<<grid, 256, 0, stream>>>(Xf, Tf, alphaTp, xfac, out);
}